// Round 7
// baseline (965.257 us; speedup 1.0000x reference)
//
#include <hip/hip_runtime.h>
#include <cstdint>

#define B_ 16
#define C_ 1024
#define Q_ 128
#define H_ 768
#define OSTR (4 * H_)  // 3072

typedef __attribute__((ext_vector_type(8))) short bf16x8;
typedef __attribute__((ext_vector_type(4))) float f32x4;
typedef __attribute__((ext_vector_type(4))) int int4v;

__device__ __forceinline__ unsigned short f2bf(float x) {
  union { float f; unsigned u; } v; v.f = x;
  unsigned r = v.u + 0x7FFFu + ((v.u >> 16) & 1u);
  return (unsigned short)(r >> 16);
}
__device__ __forceinline__ unsigned pk2(float a, float b) {
  return (unsigned)f2bf(a) | ((unsigned)f2bf(b) << 16);
}

// four-segment fp32 -> bf16 (context, query, Wc, Wq) in one launch
__global__ __launch_bounds__(256) void f2bf4_kernel(
    const float* __restrict__ s0, unsigned short* __restrict__ d0, int n0,
    const float* __restrict__ s1, unsigned short* __restrict__ d1, int n1,
    const float* __restrict__ s2, unsigned short* __restrict__ d2, int n2,
    const float* __restrict__ s3, unsigned short* __restrict__ d3, int n3) {
  int i = blockIdx.x * 256 + threadIdx.x;
  const float* s;
  unsigned short* d;
  if (i < n0) { s = s0; d = d0; }
  else if ((i -= n0) < n1) { s = s1; d = d1; }
  else if ((i -= n1) < n2) { s = s2; d = d2; }
  else if ((i -= n2) < n3) { s = s3; d = d3; }
  else return;
  float4 a = ((const float4*)s)[2 * i];
  float4 b = ((const float4*)s)[2 * i + 1];
  int4v o;
  o[0] = (int)pk2(a.x, a.y); o[1] = (int)pk2(a.z, a.w);
  o[2] = (int)pk2(b.x, b.y); o[3] = (int)pk2(b.z, b.w);
  ((int4v*)d)[i] = o;
}

// NT gemm, bf16 A and W, global_load_lds (width 16) staging, m97 structure.
// REP: diagnostic repeat factor (idempotent re-execution to surface in rocprof).
template <int MODE, int REP>
__global__ __launch_bounds__(256) void gemm_glds_nt(
    const unsigned short* __restrict__ A, const unsigned short* __restrict__ W,
    const float* __restrict__ bias, float* __restrict__ out32, int ostr,
    unsigned short* __restrict__ ob1, unsigned short* __restrict__ ob2,
    const float* __restrict__ watt, int K, int qchunk, int nbn) {
  __shared__ __align__(16) unsigned short As[128 * 32];
  __shared__ __align__(16) unsigned short Ws[128 * 32];
  const int tid = threadIdx.x;
  const int lane = tid & 63;
  const int w = tid >> 6;
  const int L = blockIdx.x;
  const int orig = (L & 7) * qchunk + (L >> 3);
  const int bm = (orig / nbn) * 128;
  const int bn = (orig % nbn) * 128;
  const int wr = (w >> 1) * 64;
  const int wc = (w & 1) * 64;
  const int fr = lane & 15;
  const int fq = lane >> 4;

  auto stage = [&](const unsigned short* __restrict__ G, unsigned short* S,
                   int brow, int k0) {
#pragma unroll
    for (int r = 0; r < 2; ++r) {
      const int c = r * 256 + w * 64 + lane;
      const int row = c >> 2, sub = c & 3;
      const unsigned short* g = G + (size_t)(brow + row) * K + k0 + sub * 8;
      unsigned short* l = S + (size_t)(r * 256 + w * 64) * 8;
      __builtin_amdgcn_global_load_lds(
          (const __attribute__((address_space(1))) void*)g,
          (__attribute__((address_space(3))) void*)l, 16, 0, 0);
    }
  };

  for (int rep = 0; rep < REP; ++rep) {
    f32x4 acc[4][4];
#pragma unroll
    for (int i = 0; i < 4; ++i)
#pragma unroll
      for (int j = 0; j < 4; ++j)
#pragma unroll
        for (int e = 0; e < 4; ++e) acc[i][j][e] = 0.f;

    for (int k0 = 0; k0 < K; k0 += 32) {
      stage(A, As, bm, k0);
      stage(W, Ws, bn, k0);
      __syncthreads();
      bf16x8 af[4], wf[4];
#pragma unroll
      for (int i = 0; i < 4; ++i)
        af[i] = *(const bf16x8*)(As + (wr + i * 16 + fr) * 32 + fq * 8);
#pragma unroll
      for (int j = 0; j < 4; ++j)
        wf[j] = *(const bf16x8*)(Ws + (wc + j * 16 + fr) * 32 + fq * 8);
#pragma unroll
      for (int i = 0; i < 4; ++i)
#pragma unroll
        for (int j = 0; j < 4; ++j)
          acc[i][j] = __builtin_amdgcn_mfma_f32_16x16x32_bf16(af[i], wf[j], acc[i][j], 0, 0, 0);
      __syncthreads();
    }

#pragma unroll
    for (int i = 0; i < 4; ++i) {
#pragma unroll
      for (int j = 0; j < 4; ++j) {
        int n = bn + wc + j * 16 + fr;
        float bb = bias[n];
        if constexpr (MODE == 0) {
#pragma unroll
          for (int r = 0; r < 4; ++r) {
            int m = bm + wr + i * 16 + fq * 4 + r;
            float v = acc[i][j][r] + bb;
            out32[(size_t)m * ostr + n] = v;
            ob1[(size_t)m * H_ + n] = f2bf(v);
          }
        } else {
          float wv = watt[n];
          ushort4 t4;
#pragma unroll
          for (int r = 0; r < 4; ++r) {
            int m = bm + wr + i * 16 + fq * 4 + r;
            float v = acc[i][j][r] + bb;
            ob1[(size_t)m * H_ + n] = f2bf(v * wv);
            (&t4.x)[r] = f2bf(v);
          }
          int bidx = bm >> 7;
          int q0 = wr + i * 16 + fq * 4;
          *(ushort4*)(ob2 + ((size_t)bidx * H_ + n) * Q_ + q0) = t4;
        }
      }
    }
    __syncthreads();
  }
}

// Fused attention: block = 32 ctx rows, 4 waves = (row-tile, q-half), grid 512.
template <int REP>
__global__ __launch_bounds__(256) void attn4_kernel(
    float* __restrict__ out, const unsigned short* __restrict__ ctxp,
    const unsigned short* __restrict__ qryW,
    const unsigned short* __restrict__ qryT, const float* __restrict__ b_att,
    const float* __restrict__ cmask, const float* __restrict__ qmask,
    float* __restrict__ q2c) {
  __shared__ __align__(16) unsigned char smem[8192 + 65536];
  __shared__ float pmS[2][32];
  __shared__ float psS[2][32];
  unsigned char* r1 = smem + 8192;
  const int tid = threadIdx.x;
  const int lane = tid & 63;
  const int w = tid >> 6;
  const int fr = lane & 15;
  const int g = lane >> 4;
  const int rt = w & 1;
  const int qh = w >> 1;
  const int L = blockIdx.x;
  const int orig = (L & 7) * 64 + (L >> 3);
  const int bc0 = orig * 32;
  const int b = bc0 >> 10;

  const int ar = tid >> 3, ak = (tid & 7) * 8;
  const int br = tid >> 1, bk = (tid & 1) * 4;
  const unsigned short* aSrcBase = ctxp + (size_t)(bc0 + ar) * H_ + ak;
  const unsigned short* bSrcBase = qryW + (size_t)(b * Q_ + br) * H_ + bk * 8;
  const int pr = tid >> 1, pc16 = (tid & 1) * 8;

  for (int rep = 0; rep < REP; ++rep) {
    f32x4 acc[4];
#pragma unroll
    for (int nf = 0; nf < 4; ++nf)
#pragma unroll
      for (int e = 0; e < 4; ++e) acc[nf][e] = 0.f;

    int4v av;
    int4v bv0, bv1, bv2, bv3;
    auto LOAD_AB = [&](int t) {
      av = *(const int4v*)(aSrcBase + t * 64);
      const int4v* bs = (const int4v*)(bSrcBase + t * 64);
      bv0 = bs[0]; bv1 = bs[1]; bv2 = bs[2]; bv3 = bs[3];
    };
    auto WRITE_AB = [&](int buf) {
      unsigned char* bA = r1 + buf * 20480;
      unsigned char* bB = bA + 4096;
      const int ck = tid & 7;
      *(int4v*)(bA + ar * 128 + ((ck ^ (ar & 7)) << 4)) = av;
      *(int4v*)(bB + br * 128 + (((bk + 0) ^ (br & 7)) << 4)) = bv0;
      *(int4v*)(bB + br * 128 + (((bk + 1) ^ (br & 7)) << 4)) = bv1;
      *(int4v*)(bB + br * 128 + (((bk + 2) ^ (br & 7)) << 4)) = bv2;
      *(int4v*)(bB + br * 128 + (((bk + 3) ^ (br & 7)) << 4)) = bv3;
    };

    LOAD_AB(0);
    WRITE_AB(0);
    __syncthreads();

    for (int t = 0; t < 12; ++t) {
      const int cur = t & 1;
      if (t < 11) LOAD_AB(t + 1);
      const unsigned char* bA = r1 + cur * 20480;
      const unsigned char* bB = bA + 4096;
      const int rowa = rt * 16 + fr;
#pragma unroll
      for (int kk = 0; kk < 2; ++kk) {
        bf16x8 af = *(const bf16x8*)(bA + rowa * 128 + (((kk * 4 + g) ^ (rowa & 7)) << 4));
#pragma unroll
        for (int nf = 0; nf < 4; ++nf) {
          const int rq = qh * 64 + nf * 16 + fr;
          bf16x8 bf = *(const bf16x8*)(bB + rq * 128 + (((kk * 4 + g) ^ (rq & 7)) << 4));
          acc[nf] = __builtin_amdgcn_mfma_f32_16x16x32_bf16(af, bf, acc[nf], 0, 0, 0);
        }
      }
      if (t < 11) WRITE_AB(cur ^ 1);
      __syncthreads();
    }

    int4v pv[8];
    auto PV_LOAD = [&](int ch) {
      const int4v* s = (const int4v*)(qryT + ((size_t)b * H_ + ch * 128 + pr) * Q_ + pc16 * 8);
#pragma unroll
      for (int i = 0; i < 8; ++i) pv[i] = s[i];
    };
    auto PV_WRITE = [&](int buf) {
      unsigned char* bP = r1 + buf * 32768;
#pragma unroll
      for (int i = 0; i < 8; ++i)
        *(int4v*)(bP + pr * 256 + (((pc16 + i) ^ (pr & 7)) << 4)) = pv[i];
    };

    float mxr[4], er[4][4];
#pragma unroll
    for (int r = 0; r < 4; ++r) {
      float mx = acc[0][r];
#pragma unroll
      for (int nf = 1; nf < 4; ++nf) mx = fmaxf(mx, acc[nf][r]);
      mx = fmaxf(mx, __shfl_xor(mx, 1));
      mx = fmaxf(mx, __shfl_xor(mx, 2));
      mx = fmaxf(mx, __shfl_xor(mx, 4));
      mx = fmaxf(mx, __shfl_xor(mx, 8));
      float s = 0.f;
#pragma unroll
      for (int nf = 0; nf < 4; ++nf) { er[r][nf] = __expf(acc[nf][r] - mx); s += er[r][nf]; }
      s += __shfl_xor(s, 1); s += __shfl_xor(s, 2);
      s += __shfl_xor(s, 4); s += __shfl_xor(s, 8);
      mxr[r] = mx;
      const int rowl = rt * 16 + g * 4 + r;
      if (fr == 0) { pmS[qh][rowl] = mx; psS[qh][rowl] = s; }
    }
    __syncthreads();
    PV_LOAD(0);
    {
      const float batt = b_att[0];
      float qm[4];
#pragma unroll
      for (int nf = 0; nf < 4; ++nf) qm[nf] = qmask[b * Q_ + qh * 64 + nf * 16 + fr];
#pragma unroll
      for (int r = 0; r < 4; ++r) {
        const int rowl = rt * 16 + g * 4 + r;
        float m0 = pmS[0][rowl], m1 = pmS[1][rowl];
        float M = fmaxf(m0, m1);
        float S = psS[0][rowl] * __expf(m0 - M) + psS[1][rowl] * __expf(m1 - M);
        if (qh == 0 && fr == 0) q2c[bc0 + rowl] = M + batt;
        float scale = __expf(mxr[r] - M) * cmask[bc0 + rowl] / S;
#pragma unroll
        for (int nf = 0; nf < 4; ++nf) {
          float al = er[r][nf] * scale * qm[nf];
          int byo = rowl * 256 + (qh * 64 + nf * 16 + fr) * 2;
          byo ^= (rowl & 7) << 4;
          *(unsigned short*)(smem + byo) = f2bf(al);
        }
      }
    }
    PV_WRITE(0);
    __syncthreads();

    bf16x8 paf[4];
    const int rowa2 = rt * 16 + fr;
#pragma unroll
    for (int kk = 0; kk < 4; ++kk)
      paf[kk] = *(const bf16x8*)(smem + rowa2 * 256 + (((kk * 4 + g) ^ (rowa2 & 7)) << 4));

    for (int ch = 0; ch < 6; ++ch) {
      const int cur = ch & 1;
      if (ch < 5) PV_LOAD(ch + 1);
      f32x4 pacc[4];
#pragma unroll
      for (int pn = 0; pn < 4; ++pn)
#pragma unroll
        for (int e = 0; e < 4; ++e) pacc[pn][e] = 0.f;
      const unsigned char* bP = r1 + cur * 32768;
#pragma unroll
      for (int pn = 0; pn < 4; ++pn) {
        const int rp = qh * 64 + pn * 16 + fr;
#pragma unroll
        for (int kk = 0; kk < 4; ++kk) {
          bf16x8 bf = *(const bf16x8*)(bP + rp * 256 + (((kk * 4 + g) ^ (rp & 7)) << 4));
          pacc[pn] = __builtin_amdgcn_mfma_f32_16x16x32_bf16(paf[kk], bf, pacc[pn], 0, 0, 0);
        }
      }
      const int p0 = ch * 128;
#pragma unroll
      for (int pn = 0; pn < 4; ++pn) {
        const int p = p0 + qh * 64 + pn * 16 + fr;
#pragma unroll
        for (int r = 0; r < 4; ++r) {
          const size_t rowg = (size_t)(bc0 + rt * 16 + g * 4 + r) * OSTR;
          float av2 = pacc[pn][r];
          float cx = out[rowg + p];
          out[rowg + H_ + p] = av2;
          out[rowg + 2 * H_ + p] = cx * av2;
        }
      }
      if (ch < 5) PV_WRITE(cur ^ 1);
      __syncthreads();
    }
    __syncthreads();
  }
}

// beta softmax + bvec + d-write fused; grid B*12 (64-p chunks), 256 threads
template <int REP>
__global__ __launch_bounds__(256) void beta3_kernel(
    float* __restrict__ out, const float* __restrict__ q2c,
    const float* __restrict__ cmask) {
  __shared__ float sh[C_];
  __shared__ float red[256];
  __shared__ float bb[64];
  const int tid = threadIdx.x;
  const int b = blockIdx.x / 12;
  const int p0 = (blockIdx.x % 12) * 64;
  for (int rep = 0; rep < REP; ++rep) {
    float v[4];
    float lm = -1e30f;
#pragma unroll
    for (int i = 0; i < 4; ++i) {
      v[i] = q2c[b * C_ + i * 256 + tid];
      lm = fmaxf(lm, v[i]);
    }
    red[tid] = lm;
    __syncthreads();
    for (int off = 128; off > 0; off >>= 1) {
      if (tid < off) red[tid] = fmaxf(red[tid], red[tid + off]);
      __syncthreads();
    }
    const float m = red[0];
    __syncthreads();
    float ls = 0.f;
#pragma unroll
    for (int i = 0; i < 4; ++i) {
      float e = __expf(v[i] - m);
      sh[i * 256 + tid] = e * cmask[b * C_ + i * 256 + tid];
      ls += e;
    }
    red[tid] = ls;
    __syncthreads();
    for (int off = 128; off > 0; off >>= 1) {
      if (tid < off) red[tid] += red[tid + off];
      __syncthreads();
    }
    const float denom = red[0];
    const int pp = tid & 63;
    const int cg = tid >> 6;
    const float* base = out + ((size_t)b * C_ + cg) * OSTR + p0 + pp;
    float acc = 0.f;
#pragma unroll 4
    for (int c = cg; c < C_; c += 4) {
      acc += sh[c] * (*base);
      base += 4 * OSTR;
    }
    __syncthreads();
    red[tid] = acc;
    __syncthreads();
    if (tid < 64)
      bb[tid] = (red[tid] + red[tid + 64] + red[tid + 128] + red[tid + 192]) / denom;
    __syncthreads();
    const float bv = bb[pp];
    float* b2 = out + ((size_t)b * C_ + cg) * OSTR + p0 + pp;
#pragma unroll 4
    for (int c = cg; c < C_; c += 4) {
      b2[3 * H_] = b2[0] * bv;
      b2 += 4 * OSTR;
    }
    __syncthreads();
  }
}

extern "C" void kernel_launch(void* const* d_in, const int* in_sizes, int n_in,
                              void* d_out, int out_size, void* d_ws, size_t ws_size,
                              hipStream_t stream) {
  const float* context = (const float*)d_in[0];
  const float* cmask   = (const float*)d_in[1];
  const float* query   = (const float*)d_in[2];
  const float* qmask   = (const float*)d_in[3];
  const float* Wc      = (const float*)d_in[4];
  const float* bc      = (const float*)d_in[5];
  const float* Wq      = (const float*)d_in[6];
  const float* bq      = (const float*)d_in[7];
  const float* w_att   = (const float*)d_in[8];
  const float* b_att   = (const float*)d_in[9];
  float* out = (float*)d_out;

  unsigned short* ws_ctxb = (unsigned short*)d_ws;
  unsigned short* ws_qinb = ws_ctxb + (size_t)B_ * C_ * H_;
  unsigned short* ws_Wcb  = ws_qinb + (size_t)B_ * Q_ * H_;
  unsigned short* ws_Wqb  = ws_Wcb + (size_t)H_ * H_;
  unsigned short* ws_qryW = ws_Wqb + (size_t)H_ * H_;
  unsigned short* ws_qryT = ws_qryW + (size_t)B_ * Q_ * H_;
  unsigned short* ws_ctxp = ws_qryT + (size_t)B_ * H_ * Q_;
  float* ws_q2c = (float*)(ws_ctxp + (size_t)B_ * C_ * H_);

  {
    const int n0 = B_ * C_ * H_ / 8;
    const int n1 = B_ * Q_ * H_ / 8;
    const int n2 = H_ * H_ / 8;
    const int n3 = n2;
    const int tot = n0 + n1 + n2 + n3;
    f2bf4_kernel<<<(tot + 255) / 256, 256, 0, stream>>>(
        context, ws_ctxb, n0, query, ws_qinb, n1, Wc, ws_Wcb, n2, Wq, ws_Wqb, n3);
  }
  // qry projection (REP=1)
  gemm_glds_nt<1, 1><<<96, 256, 0, stream>>>(
      ws_qinb, ws_Wqb, bq, nullptr, 0, ws_qryW, ws_qryT, w_att, H_, 12, 6);
  // ctx projection (REP=4 diagnostic)
  gemm_glds_nt<0, 4><<<768, 256, 0, stream>>>(
      ws_ctxb, ws_Wcb, bc, out, OSTR, ws_ctxp, nullptr, nullptr, H_, 96, 6);
  // fused attention (REP=4 diagnostic)
  attn4_kernel<4><<<(B_ * C_) / 32, 256, 0, stream>>>(
      out, ws_ctxp, ws_qryW, ws_qryT, b_att, cmask, qmask, ws_q2c);
  // beta softmax + bvec + d (REP=4 diagnostic)
  beta3_kernel<4><<<B_ * 12, 256, 0, stream>>>(out, ws_q2c, cmask);
}

// Round 8
// 184.446 us; speedup vs baseline: 5.2333x; 5.2333x over previous
//
#include <hip/hip_runtime.h>
#include <cstdint>

#define B_ 16
#define C_ 1024
#define Q_ 128
#define H_ 768
#define OSTR (4 * H_)  // 3072

typedef __attribute__((ext_vector_type(8))) short bf16x8;
typedef __attribute__((ext_vector_type(4))) float f32x4;
typedef __attribute__((ext_vector_type(4))) int int4v;

__device__ __forceinline__ unsigned short f2bf(float x) {
  union { float f; unsigned u; } v; v.f = x;
  unsigned r = v.u + 0x7FFFu + ((v.u >> 16) & 1u);
  return (unsigned short)(r >> 16);
}
__device__ __forceinline__ unsigned pk2(float a, float b) {
  return (unsigned)f2bf(a) | ((unsigned)f2bf(b) << 16);
}
__device__ __forceinline__ float bf2f(unsigned short u) {
  union { unsigned u; float f; } t; t.u = ((unsigned)u) << 16; return t.f;
}

// four-segment fp32 -> bf16 (context, query, Wc, Wq) in one launch
__global__ __launch_bounds__(256) void f2bf4_kernel(
    const float* __restrict__ s0, unsigned short* __restrict__ d0, int n0,
    const float* __restrict__ s1, unsigned short* __restrict__ d1, int n1,
    const float* __restrict__ s2, unsigned short* __restrict__ d2, int n2,
    const float* __restrict__ s3, unsigned short* __restrict__ d3, int n3) {
  int i = blockIdx.x * 256 + threadIdx.x;
  const float* s;
  unsigned short* d;
  if (i < n0) { s = s0; d = d0; }
  else if ((i -= n0) < n1) { s = s1; d = d1; }
  else if ((i -= n1) < n2) { s = s2; d = d2; }
  else if ((i -= n2) < n3) { s = s3; d = d3; }
  else return;
  float4 a = ((const float4*)s)[2 * i];
  float4 b = ((const float4*)s)[2 * i + 1];
  int4v o;
  o[0] = (int)pk2(a.x, a.y); o[1] = (int)pk2(a.z, a.w);
  o[2] = (int)pk2(b.x, b.y); o[3] = (int)pk2(b.z, b.w);
  ((int4v*)d)[i] = o;
}

// Unified NT GEMM (128x128 tile, BK=32, 4 waves, global_load_lds staging,
// bijective XCD-chunked swizzle). All operands bf16 rows of stride K.
// MODE 0: ctx proj  -> fp32 out (stride OSTR) + bf16 ctxp (ob1)
// MODE 1: qry proj  -> bf16 qryW=v*watt (ob1) + bf16 qryT transposed (ob2)
// MODE 2: sim       -> fused row-softmax -> bf16 alpha (ob1) + q2c
// MODE 3: PV        -> epilogue writes a, c=ctx*a, d=ctx*bvec to out
template <int MODE>
__global__ __launch_bounds__(256) void gemm_uni(
    const unsigned short* __restrict__ A, const unsigned short* __restrict__ Bm,
    const float* __restrict__ bias, float* __restrict__ out32,
    unsigned short* __restrict__ ob1, unsigned short* __restrict__ ob2,
    const float* __restrict__ watt, const float* __restrict__ cmask,
    const float* __restrict__ qmask, float* __restrict__ q2c,
    const float* __restrict__ bvec, int K, int qchunk) {
  __shared__ __align__(16) unsigned short As[128 * 32];
  __shared__ __align__(16) unsigned short Ws[128 * 32];
  __shared__ float pmS[2][128];
  __shared__ float psS[2][128];
  const int tid = threadIdx.x;
  const int lane = tid & 63;
  const int w = tid >> 6;
  const int orig = ((int)blockIdx.x & 7) * qchunk + ((int)blockIdx.x >> 3);
  const int wr = (w >> 1) * 64;
  const int wc = (w & 1) * 64;
  const int fr = lane & 15;
  const int fq = lane >> 4;

  int gm, gn, bb;
  const unsigned short *Ap, *Bp;
  if constexpr (MODE == 0 || MODE == 1) {
    gm = (orig / 6) * 128; gn = (orig % 6) * 128; bb = 0;
    Ap = A + (size_t)gm * K; Bp = Bm + (size_t)gn * K;
  } else if constexpr (MODE == 2) {
    bb = orig >> 3; gm = bb * C_ + (orig & 7) * 128; gn = 0;
    Ap = A + (size_t)gm * K; Bp = Bm + (size_t)bb * Q_ * K;
  } else {
    bb = orig / 48; const int rem = orig % 48;
    gm = bb * C_ + (rem / 6) * 128; gn = (rem % 6) * 128;
    Ap = A + (size_t)gm * K; Bp = Bm + ((size_t)bb * H_ + gn) * K;
  }

  auto stage = [&](const unsigned short* __restrict__ G, unsigned short* S, int k0) {
#pragma unroll
    for (int r = 0; r < 2; ++r) {
      const int c = r * 256 + w * 64 + lane;
      const int row = c >> 2, sub = c & 3;
      const unsigned short* g = G + (size_t)row * K + k0 + sub * 8;
      unsigned short* l = S + (size_t)(r * 256 + w * 64) * 8;  // wave-uniform base
      __builtin_amdgcn_global_load_lds(
          (const __attribute__((address_space(1))) void*)g,
          (__attribute__((address_space(3))) void*)l, 16, 0, 0);
    }
  };

  f32x4 acc[4][4];
#pragma unroll
  for (int i = 0; i < 4; ++i)
#pragma unroll
    for (int j = 0; j < 4; ++j)
#pragma unroll
      for (int e = 0; e < 4; ++e) acc[i][j][e] = 0.f;

  for (int k0 = 0; k0 < K; k0 += 32) {
    stage(Ap, As, k0);
    stage(Bp, Ws, k0);
    __syncthreads();
    bf16x8 af[4], wf[4];
#pragma unroll
    for (int i = 0; i < 4; ++i)
      af[i] = *(const bf16x8*)(As + (wr + i * 16 + fr) * 32 + fq * 8);
#pragma unroll
    for (int j = 0; j < 4; ++j)
      wf[j] = *(const bf16x8*)(Ws + (wc + j * 16 + fr) * 32 + fq * 8);
#pragma unroll
    for (int i = 0; i < 4; ++i)
#pragma unroll
      for (int j = 0; j < 4; ++j)
        acc[i][j] = __builtin_amdgcn_mfma_f32_16x16x32_bf16(af[i], wf[j], acc[i][j], 0, 0, 0);
    __syncthreads();
  }

  if constexpr (MODE == 0) {
#pragma unroll
    for (int j = 0; j < 4; ++j) {
      const int n = gn + wc + j * 16 + fr;
      const float bias_n = bias[n];
#pragma unroll
      for (int i = 0; i < 4; ++i) {
#pragma unroll
        for (int r = 0; r < 4; ++r) {
          const size_t m = (size_t)gm + wr + i * 16 + fq * 4 + r;
          float v = acc[i][j][r] + bias_n;
          out32[m * OSTR + n] = v;
          ob1[m * H_ + n] = f2bf(v);
        }
      }
    }
  } else if constexpr (MODE == 1) {
#pragma unroll
    for (int i = 0; i < 4; ++i) {
#pragma unroll
      for (int j = 0; j < 4; ++j) {
        const int n = gn + wc + j * 16 + fr;
        const float bias_n = bias[n];
        const float wv = watt[n];
        ushort4 t4;
#pragma unroll
        for (int r = 0; r < 4; ++r) {
          const size_t m = (size_t)gm + wr + i * 16 + fq * 4 + r;
          float v = acc[i][j][r] + bias_n;
          ob1[m * H_ + n] = f2bf(v * wv);
          (&t4.x)[r] = f2bf(v);
        }
        const int bidx = gm >> 7;
        const int q0 = wr + i * 16 + fq * 4;
        *(ushort4*)(ob2 + ((size_t)bidx * H_ + n) * Q_ + q0) = t4;
      }
    }
  } else if constexpr (MODE == 2) {
    // fused row-softmax over the 128-wide q dimension (one tile = full row)
    float red[4][4];
#pragma unroll
    for (int i = 0; i < 4; ++i)
#pragma unroll
      for (int r = 0; r < 4; ++r) {
        float mx = acc[i][0][r];
#pragma unroll
        for (int j = 1; j < 4; ++j) mx = fmaxf(mx, acc[i][j][r]);
        mx = fmaxf(mx, __shfl_xor(mx, 1));
        mx = fmaxf(mx, __shfl_xor(mx, 2));
        mx = fmaxf(mx, __shfl_xor(mx, 4));
        mx = fmaxf(mx, __shfl_xor(mx, 8));
        red[i][r] = mx;
      }
    if (fr == 0) {
#pragma unroll
      for (int i = 0; i < 4; ++i)
#pragma unroll
        for (int r = 0; r < 4; ++r)
          pmS[w & 1][wr + i * 16 + fq * 4 + r] = red[i][r];
    }
    __syncthreads();
    float qm[4];
#pragma unroll
    for (int j = 0; j < 4; ++j) qm[j] = qmask[bb * Q_ + wc + j * 16 + fr];
#pragma unroll
    for (int i = 0; i < 4; ++i)
#pragma unroll
      for (int r = 0; r < 4; ++r) {
        const int lr = wr + i * 16 + fq * 4 + r;
        const float M = fmaxf(pmS[0][lr], pmS[1][lr]);
        if ((w & 1) == 0 && fr == 0) q2c[gm + lr] = M;  // b_att cancels in both softmaxes
        float s = 0.f;
#pragma unroll
        for (int j = 0; j < 4; ++j) {
          acc[i][j][r] = __expf(acc[i][j][r] - M);
          s += acc[i][j][r];
        }
        s += __shfl_xor(s, 1); s += __shfl_xor(s, 2);
        s += __shfl_xor(s, 4); s += __shfl_xor(s, 8);
        red[i][r] = s;
      }
    if (fr == 0) {
#pragma unroll
      for (int i = 0; i < 4; ++i)
#pragma unroll
        for (int r = 0; r < 4; ++r)
          psS[w & 1][wr + i * 16 + fq * 4 + r] = red[i][r];
    }
    __syncthreads();
#pragma unroll
    for (int i = 0; i < 4; ++i)
#pragma unroll
      for (int r = 0; r < 4; ++r) {
        const int lr = wr + i * 16 + fq * 4 + r;
        const float S = psS[0][lr] + psS[1][lr];
        const float inv = cmask[gm + lr] / S;
#pragma unroll
        for (int j = 0; j < 4; ++j) {
          const int lc = wc + j * 16 + fr;
          ob1[(size_t)(gm + lr) * Q_ + lc] = f2bf(acc[i][j][r] * inv * qm[j]);
        }
      }
  } else {  // MODE 3: PV epilogue; ob1 = ctxp (bf16, read)
#pragma unroll
    for (int j = 0; j < 4; ++j) {
      const int n = gn + wc + j * 16 + fr;
      const float bv = bvec[bb * H_ + n];
#pragma unroll
      for (int i = 0; i < 4; ++i) {
#pragma unroll
        for (int r = 0; r < 4; ++r) {
          const size_t m = (size_t)gm + wr + i * 16 + fq * 4 + r;
          const float av = acc[i][j][r];
          const float cx = bf2f(ob1[m * H_ + n]);
          float* row = out32 + m * OSTR;
          row[H_ + n] = av;
          row[2 * H_ + n] = cx * av;
          row[3 * H_ + n] = cx * bv;
        }
      }
    }
  }
}

// beta softmax over c (per batch) + bvec[b,p] = sum_c beta[c]*ctx_bf16[b,c,p]
__global__ __launch_bounds__(256) void beta_bvec_kernel(
    const unsigned short* __restrict__ ctxp, const float* __restrict__ q2c,
    const float* __restrict__ cmask, float* __restrict__ bvec) {
  __shared__ float sh[C_];
  __shared__ float red[256];
  const int tid = threadIdx.x;
  const int b = blockIdx.x / 12;
  const int p0 = (blockIdx.x % 12) * 64;
  float v[4];
  float lm = -1e30f;
#pragma unroll
  for (int i = 0; i < 4; ++i) {
    v[i] = q2c[b * C_ + i * 256 + tid];
    lm = fmaxf(lm, v[i]);
  }
  red[tid] = lm;
  __syncthreads();
  for (int off = 128; off > 0; off >>= 1) {
    if (tid < off) red[tid] = fmaxf(red[tid], red[tid + off]);
    __syncthreads();
  }
  const float m = red[0];
  __syncthreads();
  float ls = 0.f;
#pragma unroll
  for (int i = 0; i < 4; ++i) {
    float e = __expf(v[i] - m);
    sh[i * 256 + tid] = e * cmask[b * C_ + i * 256 + tid];
    ls += e;
  }
  red[tid] = ls;
  __syncthreads();
  for (int off = 128; off > 0; off >>= 1) {
    if (tid < off) red[tid] += red[tid + off];
    __syncthreads();
  }
  const float denom = red[0];
  const int pp = tid & 63;
  const int cg = tid >> 6;
  const unsigned short* base = ctxp + ((size_t)(b * C_ + cg)) * H_ + p0 + pp;
  float acc = 0.f;
#pragma unroll 4
  for (int c = cg; c < C_; c += 4) {
    acc += sh[c] * bf2f(*base);
    base += (size_t)4 * H_;
  }
  __syncthreads();
  red[tid] = acc;
  __syncthreads();
  if (tid < 64)
    bvec[b * H_ + p0 + tid] =
        (red[tid] + red[tid + 64] + red[tid + 128] + red[tid + 192]) / denom;
}

extern "C" void kernel_launch(void* const* d_in, const int* in_sizes, int n_in,
                              void* d_out, int out_size, void* d_ws, size_t ws_size,
                              hipStream_t stream) {
  const float* context = (const float*)d_in[0];
  const float* cmask   = (const float*)d_in[1];
  const float* query   = (const float*)d_in[2];
  const float* qmask   = (const float*)d_in[3];
  const float* Wc      = (const float*)d_in[4];
  const float* bc      = (const float*)d_in[5];
  const float* Wq      = (const float*)d_in[6];
  const float* bq      = (const float*)d_in[7];
  const float* w_att   = (const float*)d_in[8];
  float* out = (float*)d_out;

  unsigned short* ws_ctxb = (unsigned short*)d_ws;             // B*C*H bf16 context
  unsigned short* ws_qinb = ws_ctxb + (size_t)B_ * C_ * H_;    // B*Q*H bf16 query
  unsigned short* ws_Wcb  = ws_qinb + (size_t)B_ * Q_ * H_;    // H*H
  unsigned short* ws_Wqb  = ws_Wcb + (size_t)H_ * H_;          // H*H
  unsigned short* ws_qryW = ws_Wqb + (size_t)H_ * H_;          // B*Q*H
  unsigned short* ws_qryT = ws_qryW + (size_t)B_ * Q_ * H_;    // B*H*Q
  unsigned short* ws_ctxp = ws_qryT + (size_t)B_ * H_ * Q_;    // B*C*H bf16 ctx proj
  float* ws_q2c  = (float*)(ws_ctxp + (size_t)B_ * C_ * H_);   // B*C
  float* ws_bvec = ws_q2c + (size_t)B_ * C_;                   // B*H
  // alpha (B*C*Q bf16 = 2,097,152 elems) overlays qinb+Wcb (2,162,688 elems),
  // both dead after the qry/ctx projections.
  unsigned short* ws_alpha = ws_qinb;

  // fp32 -> bf16 for all four inputs, one launch
  {
    const int n0 = B_ * C_ * H_ / 8;
    const int n1 = B_ * Q_ * H_ / 8;
    const int n2 = H_ * H_ / 8;
    const int n3 = n2;
    const int tot = n0 + n1 + n2 + n3;
    f2bf4_kernel<<<(tot + 255) / 256, 256, 0, stream>>>(
        context, ws_ctxb, n0, query, ws_qinb, n1, Wc, ws_Wcb, n2, Wq, ws_Wqb, n3);
  }
  // qry projection: qryW (w_att folded) + qryT. 96 blocks, qchunk=12.
  gemm_uni<1><<<96, 256, 0, stream>>>(
      ws_qinb, ws_Wqb, bq, nullptr, ws_qryW, ws_qryT, w_att,
      nullptr, nullptr, nullptr, nullptr, H_, 12);
  // ctx projection: fp32 out (stride 4H) + bf16 ctxp. 768 blocks, qchunk=96.
  gemm_uni<0><<<768, 256, 0, stream>>>(
      ws_ctxb, ws_Wcb, bc, out, ws_ctxp, nullptr, nullptr,
      nullptr, nullptr, nullptr, nullptr, H_, 96);
  // sim GEMM + fused softmax: alpha (bf16) + q2c. 128 blocks, qchunk=16.
  gemm_uni<2><<<128, 256, 0, stream>>>(
      ws_ctxp, ws_qryW, nullptr, nullptr, ws_alpha, nullptr, nullptr,
      cmask, qmask, ws_q2c, nullptr, H_, 16);
  // beta softmax + bvec (reads bf16 ctxp). 192 blocks.
  beta_bvec_kernel<<<B_ * 12, 256, 0, stream>>>(ws_ctxp, ws_q2c, cmask, ws_bvec);
  // PV GEMM: writes a, c=ctx*a, d=ctx*bvec. 768 blocks, K=128, qchunk=96.
  gemm_uni<3><<<768, 256, 0, stream>>>(
      ws_alpha, ws_qryT, nullptr, out, ws_ctxp, nullptr, nullptr,
      nullptr, nullptr, nullptr, ws_bvec, Q_, 96);
}